// Round 1
// baseline (81.405 us; speedup 1.0000x reference)
//
#include <hip/hip_runtime.h>

#define DIMV 96
#define NCH 24
constexpr int VOX = DIMV * DIMV * DIMV;          // 884736
constexpr int N_CUR = 150000;
constexpr int N_GLB = 200000;
constexpr int N_TGT_LOC = 100000;
constexpr int N_TGT_GLB = 120000;

// ---- output offsets (floats) ----
constexpr size_t OFF_COORDS = 0;
constexpr size_t OFF_CURVOL = 450000;                         // 150000*3
constexpr size_t OFF_GLBVOL = OFF_CURVOL + (size_t)VOX * NCH; // 21,683,664
constexpr size_t OFF_TGTVOL = OFF_GLBVOL + (size_t)VOX * NCH; // 42,917,328
constexpr size_t OFF_VALID  = OFF_TGTVOL + (size_t)VOX;       // 43,802,064
constexpr size_t OFF_VALIDT = OFF_VALID + N_GLB;              // 44,002,064

typedef float v4f __attribute__((ext_vector_type(4)));
typedef int   v4i __attribute__((ext_vector_type(4)));

constexpr int N_COORD4 = (N_CUR * 3) / 4;        // 112500 int4 copies (450000 % 4 == 0)
constexpr int NV4_WS   = (3 * VOX) / 4;          // 663552 int4 stores to init winners

__device__ __forceinline__ int voxel_of(int x, int y, int z) {
    return (x * DIMV + y) * DIMV + z;
}

// Kernel I: workspace winner init (-1) + coords int4->float4 copy.
// Replaces hipMemsetD32Async (rocclr fillBufferAligned measured at 104 GB/s
// on this 10.6 MB fill) with exact-grid v4i NT stores.
__global__ void __launch_bounds__(256) k_init(int* __restrict__ ws,
                                              const int* __restrict__ cur_coords,
                                              float* __restrict__ coords_out) {
    int i = blockIdx.x * blockDim.x + threadIdx.x;
    if (i < NV4_WS) {
        v4i m = {-1, -1, -1, -1};
        __builtin_nontemporal_store(m, (v4i*)ws + i);
    } else if (i < NV4_WS + N_COORD4) {
        int j = i - NV4_WS;
        v4i c = *(const v4i*)(cur_coords + 4 * j);
        v4f f = {(float)c.x, (float)c.y, (float)c.z, (float)c.w};
        __builtin_nontemporal_store(f, (v4f*)coords_out + j);
    }
}

// Kernel A: point work independent of current-occupancy state.
//  seg 0 [0, N_CUR):       current winner scatter (w_cur>=0 doubles as occupancy)
//  seg 1 [+N_TGT_GLB):     target-global: valid_target + winner (idx j)
//  seg 2 [+N_TGT_LOC):     target-local: winner (idx j + N_TGT_GLB)
__global__ void k_points_a(const int* __restrict__ cur_coords,
                           const int* __restrict__ tgt_coords_g,
                           const int* __restrict__ tgt_coords_l,
                           const int* __restrict__ origin,
                           int* __restrict__ w_cur,
                           int* __restrict__ w_tgt,
                           float* __restrict__ validt_out) {
    int i = blockIdx.x * blockDim.x + threadIdx.x;
    if (i < N_CUR) {
        int x = cur_coords[3 * i], y = cur_coords[3 * i + 1], z = cur_coords[3 * i + 2];
        if ((unsigned)x < DIMV && (unsigned)y < DIMV && (unsigned)z < DIMV)
            atomicMax(&w_cur[voxel_of(x, y, z)], i);   // last-write-wins = max idx
    } else if (i < N_CUR + N_TGT_GLB) {
        int j = i - N_CUR;
        int x = tgt_coords_g[3 * j]     - origin[0];
        int y = tgt_coords_g[3 * j + 1] - origin[1];
        int z = tgt_coords_g[3 * j + 2] - origin[2];
        bool inb = (unsigned)x < DIMV && (unsigned)y < DIMV && (unsigned)z < DIMV;
        validt_out[j] = inb ? 1.0f : 0.0f;
        if (inb) atomicMax(&w_tgt[voxel_of(x, y, z)], j);
    } else if (i < N_CUR + N_TGT_GLB + N_TGT_LOC) {
        int j = i - N_CUR - N_TGT_GLB;
        int x = tgt_coords_l[3 * j], y = tgt_coords_l[3 * j + 1], z = tgt_coords_l[3 * j + 2];
        if ((unsigned)x < DIMV && (unsigned)y < DIMV && (unsigned)z < DIMV)
            atomicMax(&w_tgt[voxel_of(x, y, z)], j + N_TGT_GLB);
    }
}

// Kernel B: global points — needs completed w_cur (doubles as occupancy).
__global__ void k_points_b(const int* __restrict__ glb_coords,
                           const int* __restrict__ origin,
                           const int* __restrict__ w_cur,
                           int* __restrict__ w_glb,
                           float* __restrict__ valid_out) {
    int i = blockIdx.x * blockDim.x + threadIdx.x;
    if (i >= N_GLB) return;
    int x = glb_coords[3 * i]     - origin[0];
    int y = glb_coords[3 * i + 1] - origin[1];
    int z = glb_coords[3 * i + 2] - origin[2];
    bool inb = (unsigned)x < DIMV && (unsigned)y < DIMV && (unsigned)z < DIMV;
    int cx = min(max(x, 0), DIMV - 1);
    int cy = min(max(y, 0), DIMV - 1);
    int cz = min(max(z, 0), DIMV - 1);
    bool valid = inb && (w_cur[voxel_of(cx, cy, cz)] >= 0);   // occ != 0
    valid_out[i] = valid ? 1.0f : 0.0f;
    if (valid) atomicMax(&w_glb[voxel_of(x, y, z)], i);
}

// Kernel C: one streaming pass writing all three volumes.
// 6 threads per voxel; default value or gathered winner payload; NT stores
// (streams are written once and never re-read) and NT gathers (winner
// payload rows are read exactly once -> don't evict w_* arrays from L2).
__global__ void __launch_bounds__(256) k_fill_all(
                           const int* __restrict__ w_cur,
                           const int* __restrict__ w_glb,
                           const int* __restrict__ w_tgt,
                           const float* __restrict__ cur_values,
                           const float* __restrict__ glb_values,
                           const float* __restrict__ glb_tsdf,   // [120000]
                           const float* __restrict__ loc_tsdf,   // [100000]
                           float* __restrict__ cur_out,
                           float* __restrict__ glb_out,
                           float* __restrict__ tgt_out) {
    int idx = blockIdx.x * blockDim.x + threadIdx.x;   // VOX*6
    if (idx >= VOX * 6) return;
    int v = idx / 6, q = idx - v * 6;

    int wc = w_cur[v];
    v4f cval = (v4f){0.f, 0.f, 0.f, 0.f};
    if (wc >= 0)
        cval = __builtin_nontemporal_load((const v4f*)(cur_values + (size_t)wc * NCH + q * 4));
    __builtin_nontemporal_store(cval, (v4f*)(cur_out + (size_t)v * NCH + q * 4));

    int wg = w_glb[v];
    v4f gval = (v4f){0.f, 0.f, 0.f, 0.f};
    if (wg >= 0)
        gval = __builtin_nontemporal_load((const v4f*)(glb_values + (size_t)wg * NCH + q * 4));
    __builtin_nontemporal_store(gval, (v4f*)(glb_out + (size_t)v * NCH + q * 4));

    if (q == 0) {
        int wt = w_tgt[v];
        float tval = 1.0f;
        if (wt >= 0) tval = (wt < N_TGT_GLB) ? glb_tsdf[wt] : loc_tsdf[wt - N_TGT_GLB];
        __builtin_nontemporal_store(tval, tgt_out + v);
    }
}

extern "C" void kernel_launch(void* const* d_in, const int* in_sizes, int n_in,
                              void* d_out, int out_size, void* d_ws, size_t ws_size,
                              hipStream_t stream) {
    const int*   cur_coords   = (const int*)d_in[0];
    const float* cur_values   = (const float*)d_in[1];
    const int*   glb_coords   = (const int*)d_in[2];
    const float* glb_values   = (const float*)d_in[3];
    const int*   tgt_coords_l = (const int*)d_in[4];
    const float* tgt_tsdf_l   = (const float*)d_in[5];
    const int*   tgt_coords_g = (const int*)d_in[6];
    const float* tgt_tsdf_g   = (const float*)d_in[7];
    const int*   rel_origin   = (const int*)d_in[8];

    float* out = (float*)d_out;
    int* w_cur = (int*)d_ws;         // [VOX] winner current (>=0 also = occupancy)
    int* w_glb = w_cur + VOX;        // [VOX] winner global
    int* w_tgt = w_glb + VOX;        // [VOX] winner target

    const int T = 256;
    auto blocks = [](int n) { return (n + 255) / 256; };

    // 1: winner init to -1 + coords copy (custom kernel, replaces hipMemsetD32Async)
    k_init<<<blocks(NV4_WS + N_COORD4), T, 0, stream>>>(
        (int*)d_ws, cur_coords, out + OFF_COORDS);

    // 2: winners + valid_target
    k_points_a<<<blocks(N_CUR + N_TGT_GLB + N_TGT_LOC), T, 0, stream>>>(
        cur_coords, tgt_coords_g, tgt_coords_l, rel_origin,
        w_cur, w_tgt, out + OFF_VALIDT);

    // 3: global valid + winner (w_cur doubles as occupancy)
    k_points_b<<<blocks(N_GLB), T, 0, stream>>>(
        glb_coords, rel_origin, w_cur, w_glb, out + OFF_VALID);

    // 4: one streaming fill for all three volumes
    k_fill_all<<<blocks(VOX * 6), T, 0, stream>>>(
        w_cur, w_glb, w_tgt, cur_values, glb_values, tgt_tsdf_g, tgt_tsdf_l,
        out + OFF_CURVOL, out + OFF_GLBVOL, out + OFF_TGTVOL);
}

// Round 2
// 59.034 us; speedup vs baseline: 1.3789x; 1.3789x over previous
//
#include <hip/hip_runtime.h>

#define DIMV 96
#define NCH 24
constexpr int VOX = DIMV * DIMV * DIMV;          // 884736
constexpr int N_CUR = 150000;
constexpr int N_GLB = 200000;
constexpr int N_TGT_LOC = 100000;
constexpr int N_TGT_GLB = 120000;

// ---- output offsets (floats) ----
constexpr size_t OFF_COORDS = 0;
constexpr size_t OFF_CURVOL = 450000;                         // 150000*3
constexpr size_t OFF_GLBVOL = OFF_CURVOL + (size_t)VOX * NCH; // 21,683,664
constexpr size_t OFF_TGTVOL = OFF_GLBVOL + (size_t)VOX * NCH; // 42,917,328
constexpr size_t OFF_VALID  = OFF_TGTVOL + (size_t)VOX;       // 43,802,064
constexpr size_t OFF_VALIDT = OFF_VALID + N_GLB;              // 44,002,064

typedef float v4f __attribute__((ext_vector_type(4)));
typedef int   v4i __attribute__((ext_vector_type(4)));

constexpr int N_COORD4 = (N_CUR * 3) / 4;        // 112500 int4 copies (450000 % 4 == 0)
constexpr int NV4_WS   = (3 * VOX) / 4;          // 663552 int4 stores to init winners

__device__ __forceinline__ int voxel_of(int x, int y, int z) {
    return (x * DIMV + y) * DIMV + z;
}

// Kernel I: workspace winner init (-1) + coords int4->float4 copy.
// PLAIN stores on the workspace (not NT): the winner arrays are immediately
// re-used by 570k atomics (L2-resident lines = atomics hit L2) and re-read
// by k_points_b / k_fill_all. R1 post-mortem: NT-initing them cost ~20 us.
__global__ void __launch_bounds__(256) k_init(int* __restrict__ ws,
                                              const int* __restrict__ cur_coords,
                                              float* __restrict__ coords_out) {
    int i = blockIdx.x * blockDim.x + threadIdx.x;
    if (i < NV4_WS) {
        v4i m = {-1, -1, -1, -1};
        *((v4i*)ws + i) = m;
    } else if (i < NV4_WS + N_COORD4) {
        int j = i - NV4_WS;
        v4i c = *(const v4i*)(cur_coords + 4 * j);
        v4f f = {(float)c.x, (float)c.y, (float)c.z, (float)c.w};
        *((v4f*)coords_out + j) = f;
    }
}

// Kernel A: point work independent of current-occupancy state.
//  seg 0 [0, N_CUR):       current winner scatter (w_cur>=0 doubles as occupancy)
//  seg 1 [+N_TGT_GLB):     target-global: valid_target + winner (idx j)
//  seg 2 [+N_TGT_LOC):     target-local: winner (idx j + N_TGT_GLB)
__global__ void k_points_a(const int* __restrict__ cur_coords,
                           const int* __restrict__ tgt_coords_g,
                           const int* __restrict__ tgt_coords_l,
                           const int* __restrict__ origin,
                           int* __restrict__ w_cur,
                           int* __restrict__ w_tgt,
                           float* __restrict__ validt_out) {
    int i = blockIdx.x * blockDim.x + threadIdx.x;
    if (i < N_CUR) {
        int x = cur_coords[3 * i], y = cur_coords[3 * i + 1], z = cur_coords[3 * i + 2];
        if ((unsigned)x < DIMV && (unsigned)y < DIMV && (unsigned)z < DIMV)
            atomicMax(&w_cur[voxel_of(x, y, z)], i);   // last-write-wins = max idx
    } else if (i < N_CUR + N_TGT_GLB) {
        int j = i - N_CUR;
        int x = tgt_coords_g[3 * j]     - origin[0];
        int y = tgt_coords_g[3 * j + 1] - origin[1];
        int z = tgt_coords_g[3 * j + 2] - origin[2];
        bool inb = (unsigned)x < DIMV && (unsigned)y < DIMV && (unsigned)z < DIMV;
        validt_out[j] = inb ? 1.0f : 0.0f;
        if (inb) atomicMax(&w_tgt[voxel_of(x, y, z)], j);
    } else if (i < N_CUR + N_TGT_GLB + N_TGT_LOC) {
        int j = i - N_CUR - N_TGT_GLB;
        int x = tgt_coords_l[3 * j], y = tgt_coords_l[3 * j + 1], z = tgt_coords_l[3 * j + 2];
        if ((unsigned)x < DIMV && (unsigned)y < DIMV && (unsigned)z < DIMV)
            atomicMax(&w_tgt[voxel_of(x, y, z)], j + N_TGT_GLB);
    }
}

// Kernel B: global points — needs completed w_cur (doubles as occupancy).
__global__ void k_points_b(const int* __restrict__ glb_coords,
                           const int* __restrict__ origin,
                           const int* __restrict__ w_cur,
                           int* __restrict__ w_glb,
                           float* __restrict__ valid_out) {
    int i = blockIdx.x * blockDim.x + threadIdx.x;
    if (i >= N_GLB) return;
    int x = glb_coords[3 * i]     - origin[0];
    int y = glb_coords[3 * i + 1] - origin[1];
    int z = glb_coords[3 * i + 2] - origin[2];
    bool inb = (unsigned)x < DIMV && (unsigned)y < DIMV && (unsigned)z < DIMV;
    int cx = min(max(x, 0), DIMV - 1);
    int cy = min(max(y, 0), DIMV - 1);
    int cz = min(max(z, 0), DIMV - 1);
    bool valid = inb && (w_cur[voxel_of(cx, cy, cz)] >= 0);   // occ != 0
    valid_out[i] = valid ? 1.0f : 0.0f;
    if (valid) atomicMax(&w_glb[voxel_of(x, y, z)], i);
}

// Kernel C: one streaming pass writing all three volumes.
// 6 threads per voxel; default value or gathered winner payload.
// PLAIN loads for the payload gathers (R1 revert); NT stores only for the
// write-once volume streams (proven in the 60 us baseline).
__global__ void __launch_bounds__(256) k_fill_all(
                           const int* __restrict__ w_cur,
                           const int* __restrict__ w_glb,
                           const int* __restrict__ w_tgt,
                           const float* __restrict__ cur_values,
                           const float* __restrict__ glb_values,
                           const float* __restrict__ glb_tsdf,   // [120000]
                           const float* __restrict__ loc_tsdf,   // [100000]
                           float* __restrict__ cur_out,
                           float* __restrict__ glb_out,
                           float* __restrict__ tgt_out) {
    int idx = blockIdx.x * blockDim.x + threadIdx.x;   // VOX*6
    if (idx >= VOX * 6) return;
    int v = idx / 6, q = idx - v * 6;

    int wc = w_cur[v];
    v4f cval = (v4f){0.f, 0.f, 0.f, 0.f};
    if (wc >= 0) cval = *(const v4f*)(cur_values + (size_t)wc * NCH + q * 4);
    __builtin_nontemporal_store(cval, (v4f*)(cur_out + (size_t)v * NCH + q * 4));

    int wg = w_glb[v];
    v4f gval = (v4f){0.f, 0.f, 0.f, 0.f};
    if (wg >= 0) gval = *(const v4f*)(glb_values + (size_t)wg * NCH + q * 4);
    __builtin_nontemporal_store(gval, (v4f*)(glb_out + (size_t)v * NCH + q * 4));

    if (q == 0) {
        int wt = w_tgt[v];
        float tval = 1.0f;
        if (wt >= 0) tval = (wt < N_TGT_GLB) ? glb_tsdf[wt] : loc_tsdf[wt - N_TGT_GLB];
        __builtin_nontemporal_store(tval, tgt_out + v);
    }
}

extern "C" void kernel_launch(void* const* d_in, const int* in_sizes, int n_in,
                              void* d_out, int out_size, void* d_ws, size_t ws_size,
                              hipStream_t stream) {
    const int*   cur_coords   = (const int*)d_in[0];
    const float* cur_values   = (const float*)d_in[1];
    const int*   glb_coords   = (const int*)d_in[2];
    const float* glb_values   = (const float*)d_in[3];
    const int*   tgt_coords_l = (const int*)d_in[4];
    const float* tgt_tsdf_l   = (const float*)d_in[5];
    const int*   tgt_coords_g = (const int*)d_in[6];
    const float* tgt_tsdf_g   = (const float*)d_in[7];
    const int*   rel_origin   = (const int*)d_in[8];

    float* out = (float*)d_out;
    int* w_cur = (int*)d_ws;         // [VOX] winner current (>=0 also = occupancy)
    int* w_glb = w_cur + VOX;        // [VOX] winner global
    int* w_tgt = w_glb + VOX;        // [VOX] winner target

    const int T = 256;
    auto blocks = [](int n) { return (n + 255) / 256; };

    // 1: winner init to -1 + coords copy (plain stores -> L2-resident winners)
    k_init<<<blocks(NV4_WS + N_COORD4), T, 0, stream>>>(
        (int*)d_ws, cur_coords, out + OFF_COORDS);

    // 2: winners + valid_target
    k_points_a<<<blocks(N_CUR + N_TGT_GLB + N_TGT_LOC), T, 0, stream>>>(
        cur_coords, tgt_coords_g, tgt_coords_l, rel_origin,
        w_cur, w_tgt, out + OFF_VALIDT);

    // 3: global valid + winner (w_cur doubles as occupancy)
    k_points_b<<<blocks(N_GLB), T, 0, stream>>>(
        glb_coords, rel_origin, w_cur, w_glb, out + OFF_VALID);

    // 4: one streaming fill for all three volumes
    k_fill_all<<<blocks(VOX * 6), T, 0, stream>>>(
        w_cur, w_glb, w_tgt, cur_values, glb_values, tgt_tsdf_g, tgt_tsdf_l,
        out + OFF_CURVOL, out + OFF_GLBVOL, out + OFF_TGTVOL);
}

// Round 3
// 57.965 us; speedup vs baseline: 1.4044x; 1.0184x over previous
//
#include <hip/hip_runtime.h>

#define DIMV 96
#define NCH 24
constexpr int VOX = DIMV * DIMV * DIMV;          // 884736
constexpr int N_CUR = 150000;
constexpr int N_GLB = 200000;
constexpr int N_TGT_LOC = 100000;
constexpr int N_TGT_GLB = 120000;

// ---- output offsets (floats) ----
constexpr size_t OFF_COORDS = 0;
constexpr size_t OFF_CURVOL = 450000;                         // 150000*3
constexpr size_t OFF_GLBVOL = OFF_CURVOL + (size_t)VOX * NCH; // 21,683,664
constexpr size_t OFF_TGTVOL = OFF_GLBVOL + (size_t)VOX * NCH; // 42,917,328
constexpr size_t OFF_VALID  = OFF_TGTVOL + (size_t)VOX;       // 43,802,064
constexpr size_t OFF_VALIDT = OFF_VALID + N_GLB;              // 44,002,064

typedef float v4f __attribute__((ext_vector_type(4)));
typedef int   v4i __attribute__((ext_vector_type(4)));

constexpr int N_COORD4 = (N_CUR * 3) / 4;        // 112500 int4 copies (450000 % 4 == 0)
constexpr int NV4_WS   = (3 * VOX) / 4;          // 663552 int4 stores to init winners

__device__ __forceinline__ int voxel_of(int x, int y, int z) {
    return (x * DIMV + y) * DIMV + z;
}

// Kernel I: workspace winner init (-1) + coords int4->float4 copy.
// PLAIN stores (R1 post-mortem: NT init of the atomic-hammered winner
// arrays cost ~20 us by killing their L2 residency).
__global__ void __launch_bounds__(256) k_init(int* __restrict__ ws,
                                              const int* __restrict__ cur_coords,
                                              float* __restrict__ coords_out) {
    int i = blockIdx.x * blockDim.x + threadIdx.x;
    if (i < NV4_WS) {
        v4i m = {-1, -1, -1, -1};
        *((v4i*)ws + i) = m;
    } else if (i < NV4_WS + N_COORD4) {
        int j = i - NV4_WS;
        v4i c = *(const v4i*)(cur_coords + 4 * j);
        v4f f = {(float)c.x, (float)c.y, (float)c.z, (float)c.w};
        *((v4f*)coords_out + j) = f;
    }
}

// Kernel P: ALL point scatters in one launch (R3: k_points_b's w_glb scatter
// merged in). Occupancy gating for global points moved voxel-side: scatter
// every IN-BOUNDS global point into w_glb; the fill emits its payload only
// where w_cur[v] >= 0 too. For occupied voxels the in-bounds winner ==
// valid winner; for unoccupied voxels the fill writes defaults anyway.
//  seg 0 [0, N_CUR):       current winner scatter (w_cur>=0 doubles as occupancy)
//  seg 1 [+N_TGT_GLB):     target-global: valid_target + winner (idx j)
//  seg 2 [+N_TGT_LOC):     target-local: winner (idx j + N_TGT_GLB)
//  seg 3 [+N_GLB):         global in-bounds winner scatter (no occupancy read)
__global__ void k_points(const int* __restrict__ cur_coords,
                         const int* __restrict__ tgt_coords_g,
                         const int* __restrict__ tgt_coords_l,
                         const int* __restrict__ glb_coords,
                         const int* __restrict__ origin,
                         int* __restrict__ w_cur,
                         int* __restrict__ w_tgt,
                         int* __restrict__ w_glb,
                         float* __restrict__ validt_out) {
    int i = blockIdx.x * blockDim.x + threadIdx.x;
    if (i < N_CUR) {
        int x = cur_coords[3 * i], y = cur_coords[3 * i + 1], z = cur_coords[3 * i + 2];
        if ((unsigned)x < DIMV && (unsigned)y < DIMV && (unsigned)z < DIMV)
            atomicMax(&w_cur[voxel_of(x, y, z)], i);   // last-write-wins = max idx
    } else if (i < N_CUR + N_TGT_GLB) {
        int j = i - N_CUR;
        int x = tgt_coords_g[3 * j]     - origin[0];
        int y = tgt_coords_g[3 * j + 1] - origin[1];
        int z = tgt_coords_g[3 * j + 2] - origin[2];
        bool inb = (unsigned)x < DIMV && (unsigned)y < DIMV && (unsigned)z < DIMV;
        validt_out[j] = inb ? 1.0f : 0.0f;
        if (inb) atomicMax(&w_tgt[voxel_of(x, y, z)], j);
    } else if (i < N_CUR + N_TGT_GLB + N_TGT_LOC) {
        int j = i - N_CUR - N_TGT_GLB;
        int x = tgt_coords_l[3 * j], y = tgt_coords_l[3 * j + 1], z = tgt_coords_l[3 * j + 2];
        if ((unsigned)x < DIMV && (unsigned)y < DIMV && (unsigned)z < DIMV)
            atomicMax(&w_tgt[voxel_of(x, y, z)], j + N_TGT_GLB);
    } else if (i < N_CUR + N_TGT_GLB + N_TGT_LOC + N_GLB) {
        int j = i - N_CUR - N_TGT_GLB - N_TGT_LOC;
        int x = glb_coords[3 * j]     - origin[0];
        int y = glb_coords[3 * j + 1] - origin[1];
        int z = glb_coords[3 * j + 2] - origin[2];
        if ((unsigned)x < DIMV && (unsigned)y < DIMV && (unsigned)z < DIMV)
            atomicMax(&w_glb[voxel_of(x, y, z)], j);
    }
}

// Kernel C: streaming fill of all three volumes + the per-point global
// `valid` output (same dependency level: both need completed w_cur).
// valid segment sits at LOW block indices so its latency-bound random
// w_cur reads launch before the write stream saturates HBM.
// NT stores only on the write-once streams; plain loads elsewhere.
__global__ void __launch_bounds__(256) k_fill_all(
                           const int* __restrict__ w_cur,
                           const int* __restrict__ w_glb,
                           const int* __restrict__ w_tgt,
                           const int* __restrict__ glb_coords,
                           const int* __restrict__ origin,
                           const float* __restrict__ cur_values,
                           const float* __restrict__ glb_values,
                           const float* __restrict__ glb_tsdf,   // [120000]
                           const float* __restrict__ loc_tsdf,   // [100000]
                           float* __restrict__ cur_out,
                           float* __restrict__ glb_out,
                           float* __restrict__ tgt_out,
                           float* __restrict__ valid_out) {
    int idx = blockIdx.x * blockDim.x + threadIdx.x;   // N_GLB + VOX*6
    if (idx < N_GLB) {
        int x = glb_coords[3 * idx]     - origin[0];
        int y = glb_coords[3 * idx + 1] - origin[1];
        int z = glb_coords[3 * idx + 2] - origin[2];
        bool inb = (unsigned)x < DIMV && (unsigned)y < DIMV && (unsigned)z < DIMV;
        int cx = min(max(x, 0), DIMV - 1);
        int cy = min(max(y, 0), DIMV - 1);
        int cz = min(max(z, 0), DIMV - 1);
        bool valid = inb && (w_cur[voxel_of(cx, cy, cz)] >= 0);   // occ != 0
        valid_out[idx] = valid ? 1.0f : 0.0f;
        return;
    }
    idx -= N_GLB;
    if (idx >= VOX * 6) return;
    int v = idx / 6, q = idx - v * 6;

    int wc = w_cur[v];
    v4f cval = (v4f){0.f, 0.f, 0.f, 0.f};
    if (wc >= 0) cval = *(const v4f*)(cur_values + (size_t)wc * NCH + q * 4);
    __builtin_nontemporal_store(cval, (v4f*)(cur_out + (size_t)v * NCH + q * 4));

    int wg = w_glb[v];
    v4f gval = (v4f){0.f, 0.f, 0.f, 0.f};
    if (wg >= 0 && wc >= 0)   // voxel-side occupancy gate (see k_points)
        gval = *(const v4f*)(glb_values + (size_t)wg * NCH + q * 4);
    __builtin_nontemporal_store(gval, (v4f*)(glb_out + (size_t)v * NCH + q * 4));

    if (q == 0) {
        int wt = w_tgt[v];
        float tval = 1.0f;
        if (wt >= 0) tval = (wt < N_TGT_GLB) ? glb_tsdf[wt] : loc_tsdf[wt - N_TGT_GLB];
        __builtin_nontemporal_store(tval, tgt_out + v);
    }
}

extern "C" void kernel_launch(void* const* d_in, const int* in_sizes, int n_in,
                              void* d_out, int out_size, void* d_ws, size_t ws_size,
                              hipStream_t stream) {
    const int*   cur_coords   = (const int*)d_in[0];
    const float* cur_values   = (const float*)d_in[1];
    const int*   glb_coords   = (const int*)d_in[2];
    const float* glb_values   = (const float*)d_in[3];
    const int*   tgt_coords_l = (const int*)d_in[4];
    const float* tgt_tsdf_l   = (const float*)d_in[5];
    const int*   tgt_coords_g = (const int*)d_in[6];
    const float* tgt_tsdf_g   = (const float*)d_in[7];
    const int*   rel_origin   = (const int*)d_in[8];

    float* out = (float*)d_out;
    int* w_cur = (int*)d_ws;         // [VOX] winner current (>=0 also = occupancy)
    int* w_glb = w_cur + VOX;        // [VOX] winner global (in-bounds, voxel-gated)
    int* w_tgt = w_glb + VOX;        // [VOX] winner target

    const int T = 256;
    auto blocks = [](int n) { return (n + 255) / 256; };

    // 1: winner init to -1 + coords copy (plain stores -> L2-resident winners)
    k_init<<<blocks(NV4_WS + N_COORD4), T, 0, stream>>>(
        (int*)d_ws, cur_coords, out + OFF_COORDS);

    // 2: ALL point scatters (cur, tgt-g + validt, tgt-l, glb in-bounds)
    k_points<<<blocks(N_CUR + N_TGT_GLB + N_TGT_LOC + N_GLB), T, 0, stream>>>(
        cur_coords, tgt_coords_g, tgt_coords_l, glb_coords, rel_origin,
        w_cur, w_tgt, w_glb, out + OFF_VALIDT);

    // 3: streaming fill for all three volumes + global `valid` output
    k_fill_all<<<blocks(N_GLB + VOX * 6), T, 0, stream>>>(
        w_cur, w_glb, w_tgt, glb_coords, rel_origin,
        cur_values, glb_values, tgt_tsdf_g, tgt_tsdf_l,
        out + OFF_CURVOL, out + OFF_GLBVOL, out + OFF_TGTVOL, out + OFF_VALID);
}